// Round 2
// baseline (698.047 us; speedup 1.0000x reference)
//
#include <hip/hip_runtime.h>

// SparseAttention: B=1, H=8, S=4096, D=32, fp32; mask [S,S] bool -> passed as int32.
// Dense flash-style fp32 (no max-subtraction: scores*scale ~ N(0,1), |s|<~7,
// exp never overflows; rows never fully masked due to diagonal band).
// grid = (S/QT, H); block = 256 = 4 waves; one q-row per lane, wave index = sub
// handles a 16-wide k-slice per 64-k tile. K/V staged in LDS; all K/V LDS reads
// are wave-uniform-address (broadcast, conflict-free). Partial (o,l) per sub
// reduced via LDS at the end.

#define S_   4096
#define D_   32
#define H_   8
#define QT   64
#define KT   64
#define NSUB 4
#define KPT  16   // KT / NSUB

__global__ __launch_bounds__(256, 2)
void sparse_attn_fp32(const float* __restrict__ Q, const float* __restrict__ K,
                      const float* __restrict__ V, const int* __restrict__ mask,
                      float* __restrict__ out)
{
    __shared__ float Ks[KT][D_];
    __shared__ float Vs[KT][D_];
    __shared__ float red_o[NSUB][QT][D_ + 1];  // +1 pad: conflict-free reduce
    __shared__ float red_l[NSUB][QT];

    const int h   = blockIdx.y;
    const int q0  = blockIdx.x * QT;
    const int tid = threadIdx.x;
    const int ql  = tid & 63;   // lane = local q row
    const int sub = tid >> 6;   // wave index = k-slice

    const int q = q0 + ql;
    const float scale = 0.17677669529663687f;  // 1/sqrt(32)

    // Q row pinned in registers (reused across all k)
    float4 qreg[8];
    const float4* qrow = (const float4*)(Q + ((size_t)h * S_ + q) * D_);
#pragma unroll
    for (int i = 0; i < 8; ++i) qreg[i] = qrow[i];

    float o[D_];
#pragma unroll
    for (int d = 0; d < D_; ++d) o[d] = 0.f;
    float l = 0.f;

    const float* Kh = K + (size_t)h * S_ * D_;
    const float* Vh = V + (size_t)h * S_ * D_;

    for (int jt = 0; jt < S_; jt += KT) {
        __syncthreads();
        // stage K,V tile: 64x32 floats each = 512 float4 each; coalesced
        {
            const float4* gK = (const float4*)(Kh + (size_t)jt * D_);
            const float4* gV = (const float4*)(Vh + (size_t)jt * D_);
            float4* sK = (float4*)&Ks[0][0];
            float4* sV = (float4*)&Vs[0][0];
            sK[tid]       = gK[tid];
            sK[tid + 256] = gK[tid + 256];
            sV[tid]       = gV[tid];
            sV[tid + 256] = gV[tid + 256];
        }
        __syncthreads();

        // 16 mask int32s for my (row, k-slice); 64B, aligned; L3-resident,
        // reused across the 8 heads.
        int4 m4[4];
        {
            const int4* mrow = (const int4*)(mask + (size_t)q * S_ + jt + sub * KPT);
#pragma unroll
            for (int i = 0; i < 4; ++i) m4[i] = mrow[i];
        }
        const int* mb = (const int*)m4;

#pragma unroll
        for (int kk = 0; kk < KPT; ++kk) {
            const int jl = sub * KPT + kk;      // wave-uniform -> LDS broadcast
            const float4* krow = (const float4*)&Ks[jl][0];
            float s = 0.f;
#pragma unroll
            for (int i = 0; i < 8; ++i) {
                float4 kv = krow[i];
                s += qreg[i].x * kv.x + qreg[i].y * kv.y
                   + qreg[i].z * kv.z + qreg[i].w * kv.w;
            }
            const float p = mb[kk] ? __expf(s * scale) : 0.f;
            l += p;
            const float4* vrow = (const float4*)&Vs[jl][0];
#pragma unroll
            for (int i = 0; i < 8; ++i) {
                float4 vv = vrow[i];
                o[i * 4 + 0] += p * vv.x;
                o[i * 4 + 1] += p * vv.y;
                o[i * 4 + 2] += p * vv.z;
                o[i * 4 + 3] += p * vv.w;
            }
        }
    }

    // dump partials
#pragma unroll
    for (int d = 0; d < D_; ++d) red_o[sub][ql][d] = o[d];
    red_l[sub][ql] = l;
    __syncthreads();

    // epilogue: thread -> (q = tid&63, d-group = tid>>6 covering 8 d's)
    const int eq = tid & 63;
    const int dg = tid >> 6;
    float acc[8];
#pragma unroll
    for (int i = 0; i < 8; ++i) acc[i] = 0.f;
    float lsum = 0.f;
#pragma unroll
    for (int s2 = 0; s2 < NSUB; ++s2) {
        lsum += red_l[s2][eq];
#pragma unroll
        for (int i = 0; i < 8; ++i) acc[i] += red_o[s2][eq][dg * 8 + i];
    }
    const float inv = 1.0f / lsum;  // band => row never fully masked, lsum>0
    float* orow = out + ((size_t)h * S_ + q0 + eq) * D_ + dg * 8;
#pragma unroll
    for (int i = 0; i < 8; ++i) orow[i] = acc[i] * inv;
}

extern "C" void kernel_launch(void* const* d_in, const int* in_sizes, int n_in,
                              void* d_out, int out_size, void* d_ws, size_t ws_size,
                              hipStream_t stream) {
    const float* Q = (const float*)d_in[0];
    const float* K = (const float*)d_in[1];
    const float* V = (const float*)d_in[2];
    const int* mask = (const int*)d_in[3];
    float* out = (float*)d_out;

    dim3 grid(S_ / QT, H_);
    sparse_attn_fp32<<<grid, 256, 0, stream>>>(Q, K, V, mask, out);
}

// Round 3
// 226.736 us; speedup vs baseline: 3.0787x; 3.0787x over previous
//
#include <hip/hip_runtime.h>
#include <hip/hip_bf16.h>

// SparseAttention B=1,H=8,S=4096,D=32 fp32 in/out; mask [S,S] passed as int32.
// MFMA bf16 flash: QK split-bf16 (3 mfma) for fp32-quality scores, PV bf16.
// No max-subtraction (scores bounded, rows never fully masked -> l>0).

#define S_ 4096
#define D_ 32
#define H_ 8

typedef short short8 __attribute__((ext_vector_type(8)));
typedef float float4v __attribute__((ext_vector_type(4)));
typedef unsigned short ushort_t;
typedef unsigned long long u64;

__device__ inline ushort_t f2bf(float x) {
    __hip_bfloat16 h = __float2bfloat16(x);
    return *(ushort_t*)&h;
}
__device__ inline float bf2f(ushort_t u) {
    __hip_bfloat16 h;
    *(ushort_t*)&h = u;
    return __bfloat162float(h);
}

// ---------------- pre-pass kernels ----------------

// Q: row-major bf16 hi/lo, scale*log2e folded in. e = flat index [h][q][d].
__global__ void conv_q(const float* __restrict__ Q, ushort_t* __restrict__ hi,
                       ushort_t* __restrict__ lo) {
    int e = blockIdx.x * 256 + threadIdx.x;
    const float c = 0.17677669529663687f * 1.4426950408889634f; // 1/sqrt(32)*log2e
    float v = Q[e] * c;
    ushort_t h = f2bf(v);
    hi[e] = h;
    lo[e] = f2bf(v - bf2f(h));
}

// K: B-frag-major [h][kt(64)][t16(4)][quad(4)][n(16)][j(8)], elem = K[kt*64+t16*16+n][quad*8+j]
__global__ void conv_k(const float* __restrict__ K, ushort_t* __restrict__ hi,
                       ushort_t* __restrict__ lo) {
    int e = blockIdx.x * 256 + threadIdx.x;
    int j = e & 7, n = (e >> 3) & 15, quad = (e >> 7) & 3, t16 = (e >> 9) & 3;
    int kt = (e >> 11) & 63, h = e >> 17;
    int krow = kt * 64 + t16 * 16 + n, d = quad * 8 + j;
    float v = K[((size_t)h * S_ + krow) * D_ + d];
    ushort_t uh = f2bf(v);
    hi[e] = uh;
    lo[e] = f2bf(v - bf2f(uh));
}

// V: B-frag-major [h][kt(64)][khalf(2)][dhalf(2)][quad(4)][n(16)][j(8)],
// elem = V[kt*64+khalf*32+quad*8+j][dhalf*16+n]
__global__ void conv_v(const float* __restrict__ V, ushort_t* __restrict__ vt) {
    int e = blockIdx.x * 256 + threadIdx.x;
    int j = e & 7, n = (e >> 3) & 15, quad = (e >> 7) & 3;
    int dhalf = (e >> 9) & 1, khalf = (e >> 10) & 1;
    int kt = (e >> 11) & 63, h = e >> 17;
    int krow = kt * 64 + khalf * 32 + quad * 8 + j, d = dhalf * 16 + n;
    vt[e] = f2bf(V[((size_t)h * S_ + krow) * D_ + d]);
}

// mask int32 [S][S] -> bitmask u64 [S][S/64] via ballot
__global__ void pack_mask(const int* __restrict__ m, u64* __restrict__ out) {
    int g = blockIdx.x * 4 + (threadIdx.x >> 6); // u64 index
    int lane = threadIdx.x & 63;
    int v = m[(size_t)g * 64 + lane];
    u64 b = __ballot(v != 0);
    if (lane == 0) out[g] = b;
}

// ---------------- main MFMA flash kernel ----------------

#define PS_STRIDE 72  // ushorts per Ps row: 144B = 9*16B (aligned b128), 36 banks

__device__ inline void gl_lds16(const ushort_t* g, ushort_t* l) {
    __builtin_amdgcn_global_load_lds((const __attribute__((address_space(1))) void*)g,
                                     (__attribute__((address_space(3))) void*)l,
                                     16, 0, 0);
}

__global__ __launch_bounds__(256, 2)
void attn_mfma(const ushort_t* __restrict__ Qhi, const ushort_t* __restrict__ Qlo,
               const ushort_t* __restrict__ Khi, const ushort_t* __restrict__ Klo,
               const ushort_t* __restrict__ Vt, const u64* __restrict__ mbits,
               float* __restrict__ out) {
    // 12KB staging (Khi 4K | Klo 4K | Vt 4K) + 4 waves * Ps[16][72]
    __shared__ __align__(16) ushort_t sm[6144 + 4 * 16 * PS_STRIDE];
    ushort_t* Khi_s = sm;          // 2048 ushorts
    ushort_t* Klo_s = sm + 2048;
    ushort_t* Vt_s  = sm + 4096;

    const int h = blockIdx.y;
    const int q0 = blockIdx.x * 64;
    const int tid = threadIdx.x;
    const int w = tid >> 6, l = tid & 63;
    const int n16 = l & 15, quad = l >> 4;

    ushort_t* Ps = sm + 6144 + w * 16 * PS_STRIDE;

    // Q A-frags (row-major global): lane -> row q0+w*16+n16, d = quad*8..+7
    const int qrow = q0 + w * 16 + n16;
    const size_t qoff = ((size_t)h * S_ + qrow) * D_ + quad * 8;
    const short8 qhi = *(const short8*)(Qhi + qoff);
    const short8 qlo = *(const short8*)(Qlo + qoff);

    float4v o0 = {0.f, 0.f, 0.f, 0.f};
    float4v o1 = {0.f, 0.f, 0.f, 0.f};
    float la[4] = {0.f, 0.f, 0.f, 0.f};

    const u64* mrow = mbits + ((size_t)q0 + w * 16 + quad * 4) * (S_ / 64);

    for (int kt = 0; kt < S_ / 64; ++kt) {
        __syncthreads();
        // stage this k-tile: each wave copies its 1KB chunk of each buffer
        {
            const size_t tb = ((size_t)(h * 64 + kt)) * 2048 + w * 512 + l * 8;
            gl_lds16(Khi + tb, Khi_s + w * 512);
            gl_lds16(Klo + tb, Klo_s + w * 512);
            gl_lds16(Vt  + tb, Vt_s  + w * 512);
        }
        __syncthreads();

        // mask bits: u64 per (q-row, 64k tile); rows quad*4+reg of my wave
        u64 mk0 = mrow[0 * (S_ / 64) + kt];
        u64 mk1 = mrow[1 * (S_ / 64) + kt];
        u64 mk2 = mrow[2 * (S_ / 64) + kt];
        u64 mk3 = mrow[3 * (S_ / 64) + kt];

        // QK^T: 4 score tiles of 16x16, split 3-mfma each
#pragma unroll
        for (int t16 = 0; t16 < 4; ++t16) {
            const int fo = (t16 * 4 + quad) * 128 + n16 * 8;
            const short8 bhi = *(const short8*)(Khi_s + fo);
            const short8 blo = *(const short8*)(Klo_s + fo);
            float4v c = {0.f, 0.f, 0.f, 0.f};
            c = __builtin_amdgcn_mfma_f32_16x16x32_bf16(qhi, bhi, c, 0, 0, 0);
            c = __builtin_amdgcn_mfma_f32_16x16x32_bf16(qhi, blo, c, 0, 0, 0);
            c = __builtin_amdgcn_mfma_f32_16x16x32_bf16(qlo, bhi, c, 0, 0, 0);
            const int sh = t16 * 16 + n16;
#pragma unroll
            for (int reg = 0; reg < 4; ++reg) {
                u64 mk = (reg == 0) ? mk0 : (reg == 1) ? mk1 : (reg == 2) ? mk2 : mk3;
                float p = ((mk >> sh) & 1ull) ? exp2f(c[reg]) : 0.f;
                la[reg] += p;
                Ps[(quad * 4 + reg) * PS_STRIDE + sh] = f2bf(p);
            }
        }

        // PV: P (A-frag from Ps) x V (B-frag from Vt_s)
#pragma unroll
        for (int khalf = 0; khalf < 2; ++khalf) {
            const short8 pa = *(const short8*)(Ps + n16 * PS_STRIDE + khalf * 32 + quad * 8);
            const short8 v0 = *(const short8*)(Vt_s + ((khalf * 2 + 0) * 4 + quad) * 128 + n16 * 8);
            const short8 v1 = *(const short8*)(Vt_s + ((khalf * 2 + 1) * 4 + quad) * 128 + n16 * 8);
            o0 = __builtin_amdgcn_mfma_f32_16x16x32_bf16(pa, v0, o0, 0, 0, 0);
            o1 = __builtin_amdgcn_mfma_f32_16x16x32_bf16(pa, v1, o1, 0, 0, 0);
        }
    }

    // reduce l across the 16 lanes (cols) of each quad
#pragma unroll
    for (int reg = 0; reg < 4; ++reg) {
#pragma unroll
        for (int m = 1; m <= 8; m <<= 1) la[reg] += __shfl_xor(la[reg], m);
    }

    // store: C/D layout col=n16, row=quad*4+reg; d = dhalf*16+n16
#pragma unroll
    for (int reg = 0; reg < 4; ++reg) {
        const float inv = 1.0f / la[reg]; // band => never fully masked
        const int r = q0 + w * 16 + quad * 4 + reg;
        float* orow = out + ((size_t)h * S_ + r) * D_;
        orow[n16]      = o0[reg] * inv;
        orow[16 + n16] = o1[reg] * inv;
    }
}

// ---------------- fallback fp32 kernel (R1, proven) ----------------

#define QT 64
#define KT 64
#define NSUB 4
#define KPT 16

__global__ __launch_bounds__(256, 2)
void sparse_attn_fp32(const float* __restrict__ Q, const float* __restrict__ K,
                      const float* __restrict__ V, const int* __restrict__ mask,
                      float* __restrict__ out)
{
    __shared__ float Ks[KT][D_];
    __shared__ float Vs[KT][D_];
    __shared__ float red_o[NSUB][QT][D_ + 1];
    __shared__ float red_l[NSUB][QT];

    const int h = blockIdx.y;
    const int q0 = blockIdx.x * QT;
    const int tid = threadIdx.x;
    const int ql = tid & 63;
    const int sub = tid >> 6;
    const int q = q0 + ql;
    const float scale = 0.17677669529663687f;

    float4 qreg[8];
    const float4* qrow = (const float4*)(Q + ((size_t)h * S_ + q) * D_);
#pragma unroll
    for (int i = 0; i < 8; ++i) qreg[i] = qrow[i];

    float o[D_];
#pragma unroll
    for (int d = 0; d < D_; ++d) o[d] = 0.f;
    float lsum0 = 0.f;

    const float* Kh = K + (size_t)h * S_ * D_;
    const float* Vh = V + (size_t)h * S_ * D_;

    for (int jt = 0; jt < S_; jt += KT) {
        __syncthreads();
        {
            const float4* gK = (const float4*)(Kh + (size_t)jt * D_);
            const float4* gV = (const float4*)(Vh + (size_t)jt * D_);
            float4* sK = (float4*)&Ks[0][0];
            float4* sV = (float4*)&Vs[0][0];
            sK[tid] = gK[tid]; sK[tid + 256] = gK[tid + 256];
            sV[tid] = gV[tid]; sV[tid + 256] = gV[tid + 256];
        }
        __syncthreads();

        int4 m4[4];
        {
            const int4* mr = (const int4*)(mask + (size_t)q * S_ + jt + sub * KPT);
#pragma unroll
            for (int i = 0; i < 4; ++i) m4[i] = mr[i];
        }
        const int* mb = (const int*)m4;

#pragma unroll
        for (int kk = 0; kk < KPT; ++kk) {
            const int jl = sub * KPT + kk;
            const float4* krow = (const float4*)&Ks[jl][0];
            float s = 0.f;
#pragma unroll
            for (int i = 0; i < 8; ++i) {
                float4 kv = krow[i];
                s += qreg[i].x * kv.x + qreg[i].y * kv.y + qreg[i].z * kv.z + qreg[i].w * kv.w;
            }
            const float p = mb[kk] ? __expf(s * scale) : 0.f;
            lsum0 += p;
            const float4* vrow = (const float4*)&Vs[jl][0];
#pragma unroll
            for (int i = 0; i < 8; ++i) {
                float4 vv = vrow[i];
                o[i * 4 + 0] += p * vv.x;
                o[i * 4 + 1] += p * vv.y;
                o[i * 4 + 2] += p * vv.z;
                o[i * 4 + 3] += p * vv.w;
            }
        }
    }

#pragma unroll
    for (int d = 0; d < D_; ++d) red_o[sub][ql][d] = o[d];
    red_l[sub][ql] = lsum0;
    __syncthreads();

    const int eq = tid & 63;
    const int dg = tid >> 6;
    float acc[8];
#pragma unroll
    for (int i = 0; i < 8; ++i) acc[i] = 0.f;
    float lsum = 0.f;
#pragma unroll
    for (int s2 = 0; s2 < NSUB; ++s2) {
        lsum += red_l[s2][eq];
#pragma unroll
        for (int i = 0; i < 8; ++i) acc[i] += red_o[s2][eq][dg * 8 + i];
    }
    const float inv = 1.0f / lsum;
    float* orow = out + ((size_t)h * S_ + q0 + eq) * D_ + dg * 8;
#pragma unroll
    for (int i = 0; i < 8; ++i) orow[i] = acc[i] * inv;
}

// ---------------- host ----------------

extern "C" void kernel_launch(void* const* d_in, const int* in_sizes, int n_in,
                              void* d_out, int out_size, void* d_ws, size_t ws_size,
                              hipStream_t stream) {
    const float* Q = (const float*)d_in[0];
    const float* K = (const float*)d_in[1];
    const float* V = (const float*)d_in[2];
    const int* mask = (const int*)d_in[3];
    float* out = (float*)d_out;

    const size_t MB = 1024 * 1024;
    const size_t need = 12 * MB;
    if (ws_size < need) {
        dim3 grid(S_ / QT, H_);
        sparse_attn_fp32<<<grid, 256, 0, stream>>>(Q, K, V, mask, out);
        return;
    }

    char* ws = (char*)d_ws;
    ushort_t* Qhi = (ushort_t*)(ws + 0 * MB);
    ushort_t* Qlo = (ushort_t*)(ws + 2 * MB);
    ushort_t* Khi = (ushort_t*)(ws + 4 * MB);
    ushort_t* Klo = (ushort_t*)(ws + 6 * MB);
    ushort_t* Vt  = (ushort_t*)(ws + 8 * MB);
    u64* mbits    = (u64*)(ws + 10 * MB);

    const int NE = H_ * S_ * D_; // 1M elements
    conv_q<<<NE / 256, 256, 0, stream>>>(Q, Qhi, Qlo);
    conv_k<<<NE / 256, 256, 0, stream>>>(K, Khi, Klo);
    conv_v<<<NE / 256, 256, 0, stream>>>(V, Vt);
    pack_mask<<<(S_ * (S_ / 64)) / 4, 256, 0, stream>>>(mask, mbits);

    dim3 grid(S_ / 64, H_);
    attn_mfma<<<grid, 256, 0, stream>>>(Qhi, Qlo, Khi, Klo, Vt, mbits, out);
}

// Round 5
// 200.129 us; speedup vs baseline: 3.4880x; 1.1329x over previous
//
#include <hip/hip_runtime.h>
#include <hip/hip_bf16.h>

// SparseAttention B=1,H=8,S=4096,D=32 fp32; mask [S,S] as int32.
// MFMA bf16 flash, split-hi/lo QK (fp32-quality scores), PV bf16.
// R5: R3's proven inner loop + (1) fused single prepass, (2) k-split 2 +
// combine. No perm-pack / asm micro-opts (R4's failure suspects).

#define S_  4096
#define D_  32
#define H_  8
#define HS  (H_ * S_)
#define HSD (H_ * S_ * D_)

typedef short short8 __attribute__((ext_vector_type(8)));
typedef float float4v __attribute__((ext_vector_type(4)));
typedef unsigned short ushort_t;
typedef unsigned long long u64;

__device__ inline ushort_t f2bf(float x) {
    __hip_bfloat16 h = __float2bfloat16(x);
    return *(ushort_t*)&h;
}
__device__ inline float bf2f(ushort_t u) {
    __hip_bfloat16 h; *(ushort_t*)&h = u; return __bfloat162float(h);
}

// ---------------- fused pre-pass (one launch) ----------------
// blocks [0,4096): Q hi/lo row-major, scale*log2e folded
// blocks [4096,8192): K hi/lo frag-major [h][kt][t16][quad][n][j]
// blocks [8192,12288): V frag-major [h][kt][khalf][dhalf][quad][n][j] (no perm)
// blocks [12288,28672): mask int32 -> u64 bitmask [q][S/64] (bit b = col kt*64+b)
__global__ __launch_bounds__(256)
void prepass(const float* __restrict__ Q, const float* __restrict__ K,
             const float* __restrict__ V, const int* __restrict__ mask,
             ushort_t* __restrict__ Qhi, ushort_t* __restrict__ Qlo,
             ushort_t* __restrict__ Khi, ushort_t* __restrict__ Klo,
             ushort_t* __restrict__ Vt, u64* __restrict__ mbits)
{
    const int bx = blockIdx.x;
    const int tid = threadIdx.x;
    if (bx < 4096) {
        int e = bx * 256 + tid;
        const float c = 0.17677669529663687f * 1.4426950408889634f;
        float v = Q[e] * c;
        ushort_t h = f2bf(v);
        Qhi[e] = h;
        Qlo[e] = f2bf(v - bf2f(h));
    } else if (bx < 8192) {
        int e = (bx - 4096) * 256 + tid;
        int j = e & 7, n = (e >> 3) & 15, quad = (e >> 7) & 3, t16 = (e >> 9) & 3;
        int kt = (e >> 11) & 63, h = e >> 17;
        int krow = kt * 64 + t16 * 16 + n, d = quad * 8 + j;
        float v = K[((size_t)h * S_ + krow) * D_ + d];
        ushort_t uh = f2bf(v);
        Khi[e] = uh;
        Klo[e] = f2bf(v - bf2f(uh));
    } else if (bx < 12288) {
        int e = (bx - 8192) * 256 + tid;
        int j = e & 7, n = (e >> 3) & 15, quad = (e >> 7) & 3;
        int dhalf = (e >> 9) & 1, khalf = (e >> 10) & 1;
        int kt = (e >> 11) & 63, h = e >> 17;
        int krow = kt * 64 + khalf * 32 + quad * 8 + j;
        int d = dhalf * 16 + n;
        Vt[e] = f2bf(V[((size_t)h * S_ + krow) * D_ + d]);
    } else {
        int widx = (bx - 12288) * 4 + (tid >> 6);   // [0, 65536)
        int l = tid & 63;
#pragma unroll
        for (int r = 0; r < 4; ++r) {
            int g = widx * 4 + r;                   // u64 index [0, S*(S/64))
            int v = mask[(size_t)g * 64 + l];
            u64 b = __ballot(v != 0);
            if (l == 0) mbits[g] = b;
        }
    }
}

// ---------------- main MFMA flash kernel ----------------

#define PS_STRIDE 72  // ushorts; 144B rows: b128-aligned reads, 2-way-max banks

__device__ inline void gl_lds16(const ushort_t* g, ushort_t* l) {
    __builtin_amdgcn_global_load_lds((const __attribute__((address_space(1))) void*)g,
                                     (__attribute__((address_space(3))) void*)l,
                                     16, 0, 0);
}

template<int KSPLIT>
__global__ __launch_bounds__(256, 2)
void attn_mfma(const ushort_t* __restrict__ Qhi, const ushort_t* __restrict__ Qlo,
               const ushort_t* __restrict__ Khi, const ushort_t* __restrict__ Klo,
               const ushort_t* __restrict__ Vt, const u64* __restrict__ mbits,
               float* __restrict__ outp, float* __restrict__ pl)
{
    __shared__ __align__(16) ushort_t sm[6144 + 4 * 16 * PS_STRIDE];
    ushort_t* Khi_s = sm;
    ushort_t* Klo_s = sm + 2048;
    ushort_t* Vt_s  = sm + 4096;

    const int h  = blockIdx.z;
    const int ks = blockIdx.y;
    const int q0 = blockIdx.x * 64;
    const int tid = threadIdx.x;
    const int w = tid >> 6, l = tid & 63;
    const int n16 = l & 15, quad = l >> 4;

    ushort_t* Ps = sm + 6144 + w * 16 * PS_STRIDE;

    const int qrow = q0 + w * 16 + n16;
    const size_t qoff = ((size_t)h * S_ + qrow) * D_ + quad * 8;
    const short8 qhi = *(const short8*)(Qhi + qoff);
    const short8 qlo = *(const short8*)(Qlo + qoff);

    float4v o0 = {0.f, 0.f, 0.f, 0.f};
    float4v o1 = {0.f, 0.f, 0.f, 0.f};
    float la[4] = {0.f, 0.f, 0.f, 0.f};

    const u64* mrow = mbits + ((size_t)q0 + w * 16 + quad * 4) * (S_ / 64);

    const int TPK = 64 / KSPLIT;
    const int kt0 = ks * TPK, kt1 = kt0 + TPK;

    for (int kt = kt0; kt < kt1; ++kt) {
        __syncthreads();
        const size_t tb = ((size_t)(h * 64 + kt)) * 2048 + w * 512 + l * 8;
        gl_lds16(Khi + tb, Khi_s + w * 512);
        gl_lds16(Klo + tb, Klo_s + w * 512);
        gl_lds16(Vt  + tb, Vt_s  + w * 512);
        __syncthreads();

        u64 mk0 = mrow[0 * (S_ / 64) + kt];
        u64 mk1 = mrow[1 * (S_ / 64) + kt];
        u64 mk2 = mrow[2 * (S_ / 64) + kt];
        u64 mk3 = mrow[3 * (S_ / 64) + kt];

#pragma unroll
        for (int t16 = 0; t16 < 4; ++t16) {
            const int fo = (t16 * 4 + quad) * 128 + n16 * 8;
            const short8 bhi = *(const short8*)(Khi_s + fo);
            const short8 blo = *(const short8*)(Klo_s + fo);
            float4v c = {0.f, 0.f, 0.f, 0.f};
            c = __builtin_amdgcn_mfma_f32_16x16x32_bf16(qhi, bhi, c, 0, 0, 0);
            c = __builtin_amdgcn_mfma_f32_16x16x32_bf16(qhi, blo, c, 0, 0, 0);
            c = __builtin_amdgcn_mfma_f32_16x16x32_bf16(qlo, bhi, c, 0, 0, 0);
            const int sh = t16 * 16 + n16;
#pragma unroll
            for (int reg = 0; reg < 4; ++reg) {
                u64 mk = (reg == 0) ? mk0 : (reg == 1) ? mk1 : (reg == 2) ? mk2 : mk3;
                float p = ((mk >> sh) & 1ull) ? exp2f(c[reg]) : 0.f;
                la[reg] += p;
                Ps[(quad * 4 + reg) * PS_STRIDE + sh] = f2bf(p);
            }
        }

#pragma unroll
        for (int khalf = 0; khalf < 2; ++khalf) {
            const short8 pa = *(const short8*)(Ps + n16 * PS_STRIDE + khalf * 32 + quad * 8);
            const short8 v0 = *(const short8*)(Vt_s + ((khalf * 2 + 0) * 4 + quad) * 128 + n16 * 8);
            const short8 v1 = *(const short8*)(Vt_s + ((khalf * 2 + 1) * 4 + quad) * 128 + n16 * 8);
            o0 = __builtin_amdgcn_mfma_f32_16x16x32_bf16(pa, v0, o0, 0, 0, 0);
            o1 = __builtin_amdgcn_mfma_f32_16x16x32_bf16(pa, v1, o1, 0, 0, 0);
        }
    }

#pragma unroll
    for (int reg = 0; reg < 4; ++reg)
#pragma unroll
        for (int m = 1; m <= 8; m <<= 1) la[reg] += __shfl_xor(la[reg], m);

    if (KSPLIT == 1) {
#pragma unroll
        for (int reg = 0; reg < 4; ++reg) {
            const float inv = 1.0f / la[reg];   // band => l > 0
            const int r = q0 + w * 16 + quad * 4 + reg;
            float* orow = outp + ((size_t)h * S_ + r) * D_;
            orow[n16]      = o0[reg] * inv;
            orow[16 + n16] = o1[reg] * inv;
        }
    } else {
#pragma unroll
        for (int reg = 0; reg < 4; ++reg) {
            const int r = q0 + w * 16 + quad * 4 + reg;
            float* orow = outp + ((size_t)(ks * H_ + h) * S_ + r) * D_;
            orow[n16]      = o0[reg];
            orow[16 + n16] = o1[reg];
            if (n16 == 0) pl[(size_t)ks * HS + h * S_ + r] = la[reg];
        }
    }
}

__global__ __launch_bounds__(256)
void combine(const float* __restrict__ po, const float* __restrict__ pl,
             float* __restrict__ out)
{
    int e = blockIdx.x * 256 + threadIdx.x;
    int hq = e >> 5;
    float inv = 1.0f / (pl[hq] + pl[HS + hq]);
    out[e] = (po[e] + po[HSD + e]) * inv;
}

// ---------------- fallback fp32 kernel (proven) ----------------

#define QT 64
#define KT 64
#define NSUB 4
#define KPT 16

__global__ __launch_bounds__(256, 2)
void sparse_attn_fp32(const float* __restrict__ Q, const float* __restrict__ K,
                      const float* __restrict__ V, const int* __restrict__ mask,
                      float* __restrict__ out)
{
    __shared__ float Ks[KT][D_];
    __shared__ float Vs[KT][D_];
    __shared__ float red_o[NSUB][QT][D_ + 1];
    __shared__ float red_l[NSUB][QT];

    const int h = blockIdx.y;
    const int q0 = blockIdx.x * QT;
    const int tid = threadIdx.x;
    const int ql = tid & 63;
    const int sub = tid >> 6;
    const int q = q0 + ql;
    const float scale = 0.17677669529663687f;

    float4 qreg[8];
    const float4* qrow = (const float4*)(Q + ((size_t)h * S_ + q) * D_);
#pragma unroll
    for (int i = 0; i < 8; ++i) qreg[i] = qrow[i];

    float o[D_];
#pragma unroll
    for (int d = 0; d < D_; ++d) o[d] = 0.f;
    float lsum0 = 0.f;

    const float* Kh = K + (size_t)h * S_ * D_;
    const float* Vh = V + (size_t)h * S_ * D_;

    for (int jt = 0; jt < S_; jt += KT) {
        __syncthreads();
        {
            const float4* gK = (const float4*)(Kh + (size_t)jt * D_);
            const float4* gV = (const float4*)(Vh + (size_t)jt * D_);
            float4* sK = (float4*)&Ks[0][0];
            float4* sV = (float4*)&Vs[0][0];
            sK[tid] = gK[tid]; sK[tid + 256] = gK[tid + 256];
            sV[tid] = gV[tid]; sV[tid + 256] = gV[tid + 256];
        }
        __syncthreads();

        int4 m4[4];
        {
            const int4* mr = (const int4*)(mask + (size_t)q * S_ + jt + sub * KPT);
#pragma unroll
            for (int i = 0; i < 4; ++i) m4[i] = mr[i];
        }
        const int* mb = (const int*)m4;

#pragma unroll
        for (int kk = 0; kk < KPT; ++kk) {
            const int jl = sub * KPT + kk;
            const float4* krow = (const float4*)&Ks[jl][0];
            float s = 0.f;
#pragma unroll
            for (int i = 0; i < 8; ++i) {
                float4 kv = krow[i];
                s += qreg[i].x * kv.x + qreg[i].y * kv.y + qreg[i].z * kv.z + qreg[i].w * kv.w;
            }
            const float p = mb[kk] ? __expf(s * scale) : 0.f;
            lsum0 += p;
            const float4* vrow = (const float4*)&Vs[jl][0];
#pragma unroll
            for (int i = 0; i < 8; ++i) {
                float4 vv = vrow[i];
                o[i * 4 + 0] += p * vv.x;
                o[i * 4 + 1] += p * vv.y;
                o[i * 4 + 2] += p * vv.z;
                o[i * 4 + 3] += p * vv.w;
            }
        }
    }

#pragma unroll
    for (int d = 0; d < D_; ++d) red_o[sub][ql][d] = o[d];
    red_l[sub][ql] = lsum0;
    __syncthreads();

    const int eq = tid & 63;
    const int dg = tid >> 6;
    float acc[8];
#pragma unroll
    for (int i = 0; i < 8; ++i) acc[i] = 0.f;
    float lsum = 0.f;
#pragma unroll
    for (int s2 = 0; s2 < NSUB; ++s2) {
        lsum += red_l[s2][eq];
#pragma unroll
        for (int i = 0; i < 8; ++i) acc[i] += red_o[s2][eq][dg * 8 + i];
    }
    const float inv = 1.0f / lsum;
    float* orow = out + ((size_t)h * S_ + q0 + eq) * D_ + dg * 8;
#pragma unroll
    for (int i = 0; i < 8; ++i) orow[i] = acc[i] * inv;
}

// ---------------- host ----------------

extern "C" void kernel_launch(void* const* d_in, const int* in_sizes, int n_in,
                              void* d_out, int out_size, void* d_ws, size_t ws_size,
                              hipStream_t stream) {
    const float* Q = (const float*)d_in[0];
    const float* K = (const float*)d_in[1];
    const float* V = (const float*)d_in[2];
    const int* mask = (const int*)d_in[3];
    float* out = (float*)d_out;

    const size_t MB = 1024 * 1024;
    if (ws_size < 12 * MB) {
        dim3 grid(S_ / QT, H_);
        sparse_attn_fp32<<<grid, 256, 0, stream>>>(Q, K, V, mask, out);
        return;
    }

    char* ws = (char*)d_ws;
    ushort_t* Qhi = (ushort_t*)(ws + 0 * MB);
    ushort_t* Qlo = (ushort_t*)(ws + 2 * MB);
    ushort_t* Khi = (ushort_t*)(ws + 4 * MB);
    ushort_t* Klo = (ushort_t*)(ws + 6 * MB);
    ushort_t* Vt  = (ushort_t*)(ws + 8 * MB);
    u64* mbits    = (u64*)(ws + 10 * MB);     // 2 MB
    float* po     = (float*)(ws + 12 * MB);   // 8 MB (2 splits)
    float* pl     = (float*)(ws + 20 * MB);   // 256 KB

    prepass<<<28672, 256, 0, stream>>>(Q, K, V, mask, Qhi, Qlo, Khi, Klo, Vt, mbits);

    if (ws_size >= 21 * MB) {
        dim3 grid(S_ / 64, 2, H_);
        attn_mfma<2><<<grid, 256, 0, stream>>>(Qhi, Qlo, Khi, Klo, Vt, mbits, po, pl);
        combine<<<HSD / 256, 256, 0, stream>>>(po, pl, out);
    } else {
        dim3 grid(S_ / 64, 1, H_);
        attn_mfma<1><<<grid, 256, 0, stream>>>(Qhi, Qlo, Khi, Klo, Vt, mbits, out, nullptr);
    }
}

// Round 7
// 174.203 us; speedup vs baseline: 4.0071x; 1.1488x over previous
//
#include <hip/hip_runtime.h>
#include <hip/hip_bf16.h>

// SparseAttention B=1,H=8,S=4096,D=32 fp32; mask [S,S] as int32.
// MFMA bf16 flash, split-hi/lo QK (fp32-quality scores), PV bf16.
// R7: NO inline asm in MFMA kernel (CDNA MFMA->VALU hazards are software-
// managed; INLINEASM bypasses the hazard recognizer => R4/R6 corruption).
// Keeps: vectorized fused prepass, per-lane u16 mask repack, perm-packed P
// (b64 stores + k-permuted V + compiler fence), k-split 2, float4 combine.

#define S_  4096
#define D_  32
#define H_  8
#define HS  (H_ * S_)
#define HSD (H_ * S_ * D_)

typedef short short8 __attribute__((ext_vector_type(8)));
typedef short short4v __attribute__((ext_vector_type(4)));
typedef float float4v __attribute__((ext_vector_type(4)));
typedef unsigned short ushort_t;
typedef unsigned long long u64;
typedef unsigned int u32;

__device__ inline ushort_t f2bf(float x) {
    __hip_bfloat16 h = __float2bfloat16(x);
    return *(ushort_t*)&h;
}
__device__ inline float bf2f(ushort_t u) {
    __hip_bfloat16 h; *(ushort_t*)&h = u; return __bfloat162float(h);
}
__device__ inline u32 fbits(float x) {
    union { float f; u32 u; } c; c.f = x; return c.u;
}
__device__ inline void hilo(float v, ushort_t& h, ushort_t& lo) {
    h = f2bf(v);
    lo = f2bf(v - bf2f(h));
}

// ---------------- fused pre-pass (one launch, vectorized) ----------------
// blocks [0,512): Q hi/lo row-major, scale*log2e folded (8 elems/thread)
// blocks [512,1024): K hi/lo frag-major [h][kt][t16][quad][n][j]
// blocks [1024,1536): V frag-major [h][kt][khalf][dhalf][quad][n][j], rows
//   k-PERMUTED: frag k-pos p holds row (p&3)*16 + (p>>2)
// blocks [1536,5632): mask -> per-lane u16 mlane[qt16][kt][lane],
//   bit (t16*4+reg) = mask[qt16*16+(lane>>4)*4+reg][kt*64+t16*16+(lane&15)]
__global__ __launch_bounds__(256)
void prepass(const float* __restrict__ Q, const float* __restrict__ K,
             const float* __restrict__ V, const int* __restrict__ mask,
             ushort_t* __restrict__ Qhi, ushort_t* __restrict__ Qlo,
             ushort_t* __restrict__ Khi, ushort_t* __restrict__ Klo,
             ushort_t* __restrict__ Vt, ushort_t* __restrict__ mlane)
{
    const int bx = blockIdx.x;
    const int tid = threadIdx.x;
    union U8 { ushort_t u[8]; short8 v; };

    if (bx < 512) {
        const int e0 = (bx * 256 + tid) * 8;
        const float c = 0.17677669529663687f * 1.4426950408889634f;
        float4 a = *(const float4*)(Q + e0);
        float4 b = *(const float4*)(Q + e0 + 4);
        float f[8] = {a.x*c, a.y*c, a.z*c, a.w*c, b.x*c, b.y*c, b.z*c, b.w*c};
        U8 hi, lo;
#pragma unroll
        for (int i = 0; i < 8; ++i) hilo(f[i], hi.u[i], lo.u[i]);
        *(short8*)(Qhi + e0) = hi.v;
        *(short8*)(Qlo + e0) = lo.v;
    } else if (bx < 1024) {
        const int e0 = ((bx - 512) * 256 + tid) * 8;
        const int n = (e0 >> 3) & 15, quad = (e0 >> 7) & 3, t16 = (e0 >> 9) & 3;
        const int kt = (e0 >> 11) & 63, h = e0 >> 17;
        const int krow = kt * 64 + t16 * 16 + n;
        const float* src = K + ((size_t)h * S_ + krow) * D_ + quad * 8;
        float4 a = *(const float4*)src;
        float4 b = *(const float4*)(src + 4);
        float f[8] = {a.x, a.y, a.z, a.w, b.x, b.y, b.z, b.w};
        U8 hi, lo;
#pragma unroll
        for (int i = 0; i < 8; ++i) hilo(f[i], hi.u[i], lo.u[i]);
        *(short8*)(Khi + e0) = hi.v;
        *(short8*)(Klo + e0) = lo.v;
    } else if (bx < 1536) {
        const int e0 = ((bx - 1024) * 256 + tid) * 8;
        const int n = (e0 >> 3) & 15, quad = (e0 >> 7) & 3;
        const int dhalf = (e0 >> 9) & 1, khalf = (e0 >> 10) & 1;
        const int kt = (e0 >> 11) & 63, h = e0 >> 17;
        const int d = dhalf * 16 + n;
        const int pbase = khalf * 32 + quad * 8;
        U8 o;
#pragma unroll
        for (int j = 0; j < 8; ++j) {
            int p = pbase + j;
            int krow = kt * 64 + (p & 3) * 16 + (p >> 2);   // permuted row
            o.u[j] = f2bf(V[((size_t)h * S_ + krow) * D_ + d]);
        }
        *(short8*)(Vt + e0) = o.v;
    } else {
        const int pairi = (bx - 1536) * 4 + (tid >> 6);   // (qt16,kt) in [0,16384)
        const int l = tid & 63;
        const int qt16 = pairi >> 6, kt = pairi & 63;
        const int row0 = qt16 * 16 + (l >> 4) * 4;
        const int col0 = kt * 64 + (l & 15);
        u32 ml = 0;
#pragma unroll
        for (int t16 = 0; t16 < 4; ++t16)
#pragma unroll
            for (int reg = 0; reg < 4; ++reg) {
                int v = mask[(size_t)(row0 + reg) * S_ + col0 + t16 * 16];
                ml |= (v != 0 ? 1u : 0u) << (t16 * 4 + reg);
            }
        mlane[(size_t)pairi * 64 + l] = (ushort_t)ml;
    }
}

// ---------------- main MFMA flash kernel ----------------

#define PS_STRIDE 72  // ushorts; 144B rows

__device__ inline void gl_lds16(const ushort_t* g, ushort_t* l) {
    __builtin_amdgcn_global_load_lds((const __attribute__((address_space(1))) void*)g,
                                     (__attribute__((address_space(3))) void*)l,
                                     16, 0, 0);
}

template<int KSPLIT>
__global__ __launch_bounds__(256, 4)
void attn_mfma(const ushort_t* __restrict__ Qhi, const ushort_t* __restrict__ Qlo,
               const ushort_t* __restrict__ Khi, const ushort_t* __restrict__ Klo,
               const ushort_t* __restrict__ Vt, const ushort_t* __restrict__ mlane,
               float* __restrict__ outp, float* __restrict__ pl)
{
    __shared__ __align__(16) ushort_t sm[6144 + 4 * 16 * PS_STRIDE];
    ushort_t* Khi_s = sm;
    ushort_t* Klo_s = sm + 2048;
    ushort_t* Vt_s  = sm + 4096;

    const int h  = blockIdx.z;
    const int ks = blockIdx.y;
    const int q0 = blockIdx.x * 64;
    const int tid = threadIdx.x;
    const int w = tid >> 6, l = tid & 63;
    const int n16 = l & 15, quad = l >> 4;

    ushort_t* Ps = sm + 6144 + w * 16 * PS_STRIDE;

    const int qt16_u = __builtin_amdgcn_readfirstlane(blockIdx.x * 4 + w);
    const ushort_t* mlw = mlane + ((size_t)qt16_u << 12);  // [kt][lane]

    const int qrow = q0 + w * 16 + n16;
    const size_t qoff = ((size_t)h * S_ + qrow) * D_ + quad * 8;
    const short8 qhi = *(const short8*)(Qhi + qoff);
    const short8 qlo = *(const short8*)(Qlo + qoff);

    float4v o0 = {0.f, 0.f, 0.f, 0.f};
    float4v o1 = {0.f, 0.f, 0.f, 0.f};
    float la[4] = {0.f, 0.f, 0.f, 0.f};

    const int TPK = 64 / KSPLIT;
    const int kt0 = ks * TPK, kt1 = kt0 + TPK;

    for (int kt = kt0; kt < kt1; ++kt) {
        __syncthreads();
        const size_t tb = ((size_t)(h * 64 + kt)) * 2048 + w * 512 + l * 8;
        gl_lds16(Khi + tb, Khi_s + w * 512);
        gl_lds16(Klo + tb, Klo_s + w * 512);
        gl_lds16(Vt  + tb, Vt_s  + w * 512);

        const u32 ml = mlw[kt * 64 + l];   // per-lane 16 mask bits, coalesced
        __syncthreads();

        float pv[4][4];
#pragma unroll
        for (int t16 = 0; t16 < 4; ++t16) {
            const int fo = (t16 * 4 + quad) * 128 + n16 * 8;
            const short8 bhi = *(const short8*)(Khi_s + fo);
            const short8 blo = *(const short8*)(Klo_s + fo);
            float4v c = {0.f, 0.f, 0.f, 0.f};
            c = __builtin_amdgcn_mfma_f32_16x16x32_bf16(qhi, bhi, c, 0, 0, 0);
            c = __builtin_amdgcn_mfma_f32_16x16x32_bf16(qhi, blo, c, 0, 0, 0);
            c = __builtin_amdgcn_mfma_f32_16x16x32_bf16(qlo, bhi, c, 0, 0, 0);
#pragma unroll
            for (int reg = 0; reg < 4; ++reg) {
                float e = exp2f(c[reg]);
                float p = (ml & (1u << (t16 * 4 + reg))) ? e : 0.f;
                la[reg] += p;
                pv[t16][reg] = p;
            }
        }
        // pack 4 t16-values per reg -> one b64 store at permuted positions
        // pos = n16*4 + t16  (P_perm[r][pos] = P[r][(pos&3)*16 + (pos>>2)])
#pragma unroll
        for (int reg = 0; reg < 4; ++reg) {
            u32 b0 = fbits(pv[0][reg]) + 0x8000u;
            u32 b1 = fbits(pv[1][reg]) + 0x8000u;
            u32 b2 = fbits(pv[2][reg]) + 0x8000u;
            u32 b3 = fbits(pv[3][reg]) + 0x8000u;
            u32 lo_ = __builtin_amdgcn_perm(b1, b0, 0x07060302u);
            u32 hi_ = __builtin_amdgcn_perm(b3, b2, 0x07060302u);
            union { u32 wds[2]; short4v s; } pk;
            pk.wds[0] = lo_; pk.wds[1] = hi_;
            *(short4v*)(Ps + (quad * 4 + reg) * PS_STRIDE + n16 * 4) = pk.s;
        }
        // compiler fence: keep P stores ordered before P loads
        asm volatile("" ::: "memory");

#pragma unroll
        for (int khalf = 0; khalf < 2; ++khalf) {
            const short8 pa = *(const short8*)(Ps + n16 * PS_STRIDE + khalf * 32 + quad * 8);
            const short8 v0 = *(const short8*)(Vt_s + ((khalf * 2 + 0) * 4 + quad) * 128 + n16 * 8);
            const short8 v1 = *(const short8*)(Vt_s + ((khalf * 2 + 1) * 4 + quad) * 128 + n16 * 8);
            o0 = __builtin_amdgcn_mfma_f32_16x16x32_bf16(pa, v0, o0, 0, 0, 0);
            o1 = __builtin_amdgcn_mfma_f32_16x16x32_bf16(pa, v1, o1, 0, 0, 0);
        }
    }

#pragma unroll
    for (int reg = 0; reg < 4; ++reg)
#pragma unroll
        for (int m = 1; m <= 8; m <<= 1) la[reg] += __shfl_xor(la[reg], m);

    if (KSPLIT == 1) {
#pragma unroll
        for (int reg = 0; reg < 4; ++reg) {
            const float inv = 1.0f / la[reg];   // band => l > 0
            const int r = q0 + w * 16 + quad * 4 + reg;
            float* orow = outp + ((size_t)h * S_ + r) * D_;
            orow[n16]      = o0[reg] * inv;
            orow[16 + n16] = o1[reg] * inv;
        }
    } else {
#pragma unroll
        for (int reg = 0; reg < 4; ++reg) {
            const int r = q0 + w * 16 + quad * 4 + reg;
            float* orow = outp + ((size_t)(ks * H_ + h) * S_ + r) * D_;
            orow[n16]      = o0[reg];
            orow[16 + n16] = o1[reg];
            if (n16 == 0) pl[(size_t)ks * HS + h * S_ + r] = la[reg];
        }
    }
}

__global__ __launch_bounds__(256)
void combine(const float* __restrict__ po, const float* __restrict__ pl,
             float* __restrict__ out)
{
    int e4 = (blockIdx.x * 256 + threadIdx.x) * 4;
    int hq = e4 >> 5;
    float4 x0 = *(const float4*)(po + e4);
    float4 x1 = *(const float4*)(po + HSD + e4);
    float inv = 1.0f / (pl[hq] + pl[HS + hq]);
    float4 r; r.x = (x0.x + x1.x) * inv; r.y = (x0.y + x1.y) * inv;
    r.z = (x0.z + x1.z) * inv; r.w = (x0.w + x1.w) * inv;
    *(float4*)(out + e4) = r;
}

// ---------------- fallback fp32 kernel (proven) ----------------

#define QT 64
#define KT 64
#define NSUB 4
#define KPT 16

__global__ __launch_bounds__(256, 2)
void sparse_attn_fp32(const float* __restrict__ Q, const float* __restrict__ K,
                      const float* __restrict__ V, const int* __restrict__ mask,
                      float* __restrict__ out)
{
    __shared__ float Ks[KT][D_];
    __shared__ float Vs[KT][D_];
    __shared__ float red_o[NSUB][QT][D_ + 1];
    __shared__ float red_l[NSUB][QT];

    const int h = blockIdx.y;
    const int q0 = blockIdx.x * QT;
    const int tid = threadIdx.x;
    const int ql = tid & 63;
    const int sub = tid >> 6;
    const int q = q0 + ql;
    const float scale = 0.17677669529663687f;

    float4 qreg[8];
    const float4* qrow = (const float4*)(Q + ((size_t)h * S_ + q) * D_);
#pragma unroll
    for (int i = 0; i < 8; ++i) qreg[i] = qrow[i];

    float o[D_];
#pragma unroll
    for (int d = 0; d < D_; ++d) o[d] = 0.f;
    float lsum0 = 0.f;

    const float* Kh = K + (size_t)h * S_ * D_;
    const float* Vh = V + (size_t)h * S_ * D_;

    for (int jt = 0; jt < S_; jt += KT) {
        __syncthreads();
        {
            const float4* gK = (const float4*)(Kh + (size_t)jt * D_);
            const float4* gV = (const float4*)(Vh + (size_t)jt * D_);
            float4* sK = (float4*)&Ks[0][0];
            float4* sV = (float4*)&Vs[0][0];
            sK[tid] = gK[tid]; sK[tid + 256] = gK[tid + 256];
            sV[tid] = gV[tid]; sV[tid + 256] = gV[tid + 256];
        }
        __syncthreads();

        int4 m4[4];
        {
            const int4* mr = (const int4*)(mask + (size_t)q * S_ + jt + sub * KPT);
#pragma unroll
            for (int i = 0; i < 4; ++i) m4[i] = mr[i];
        }
        const int* mb = (const int*)m4;

#pragma unroll
        for (int kk = 0; kk < KPT; ++kk) {
            const int jl = sub * KPT + kk;
            const float4* krow = (const float4*)&Ks[jl][0];
            float s = 0.f;
#pragma unroll
            for (int i = 0; i < 8; ++i) {
                float4 kv = krow[i];
                s += qreg[i].x * kv.x + qreg[i].y * kv.y + qreg[i].z * kv.z + qreg[i].w * kv.w;
            }
            const float p = mb[kk] ? __expf(s * scale) : 0.f;
            lsum0 += p;
            const float4* vrow = (const float4*)&Vs[jl][0];
#pragma unroll
            for (int i = 0; i < 8; ++i) {
                float4 vv = vrow[i];
                o[i * 4 + 0] += p * vv.x;
                o[i * 4 + 1] += p * vv.y;
                o[i * 4 + 2] += p * vv.z;
                o[i * 4 + 3] += p * vv.w;
            }
        }
    }

#pragma unroll
    for (int d = 0; d < D_; ++d) red_o[sub][ql][d] = o[d];
    red_l[sub][ql] = lsum0;
    __syncthreads();

    const int eq = tid & 63;
    const int dg = tid >> 6;
    float acc[8];
#pragma unroll
    for (int i = 0; i < 8; ++i) acc[i] = 0.f;
    float lsum = 0.f;
#pragma unroll
    for (int s2 = 0; s2 < NSUB; ++s2) {
        lsum += red_l[s2][eq];
#pragma unroll
        for (int i = 0; i < 8; ++i) acc[i] += red_o[s2][eq][dg * 8 + i];
    }
    const float inv = 1.0f / lsum;
    float* orow = out + ((size_t)h * S_ + q0 + eq) * D_ + dg * 8;
#pragma unroll
    for (int i = 0; i < 8; ++i) orow[i] = acc[i] * inv;
}

// ---------------- host ----------------

extern "C" void kernel_launch(void* const* d_in, const int* in_sizes, int n_in,
                              void* d_out, int out_size, void* d_ws, size_t ws_size,
                              hipStream_t stream) {
    const float* Q = (const float*)d_in[0];
    const float* K = (const float*)d_in[1];
    const float* V = (const float*)d_in[2];
    const int* mask = (const int*)d_in[3];
    float* out = (float*)d_out;

    const size_t MB = 1024 * 1024;
    if (ws_size < 12 * MB) {
        dim3 grid(S_ / QT, H_);
        sparse_attn_fp32<<<grid, 256, 0, stream>>>(Q, K, V, mask, out);
        return;
    }

    char* ws = (char*)d_ws;
    ushort_t* Qhi = (ushort_t*)(ws + 0 * MB);
    ushort_t* Qlo = (ushort_t*)(ws + 2 * MB);
    ushort_t* Khi = (ushort_t*)(ws + 4 * MB);
    ushort_t* Klo = (ushort_t*)(ws + 6 * MB);
    ushort_t* Vt  = (ushort_t*)(ws + 8 * MB);
    ushort_t* mlane = (ushort_t*)(ws + 10 * MB); // 2 MB
    float* po     = (float*)(ws + 12 * MB);      // 8 MB (2 splits)
    float* pl     = (float*)(ws + 20 * MB);      // 256 KB

    prepass<<<5632, 256, 0, stream>>>(Q, K, V, mask, Qhi, Qlo, Khi, Klo, Vt, mlane);

    if (ws_size >= 21 * MB) {
        dim3 grid(S_ / 64, 2, H_);
        attn_mfma<2><<<grid, 256, 0, stream>>>(Qhi, Qlo, Khi, Klo, Vt, mlane, po, pl);
        combine<<<HSD / (256 * 4), 256, 0, stream>>>(po, pl, out);
    } else {
        dim3 grid(S_ / 64, 1, H_);
        attn_mfma<1><<<grid, 256, 0, stream>>>(Qhi, Qlo, Khi, Klo, Vt, mlane, out, nullptr);
    }
}